// Round 5
// baseline (442.525 us; speedup 1.0000x reference)
//
#include <hip/hip_runtime.h>
#include <math.h>
#include <stdint.h>

#define NTOK   16384
#define DIM    4096
#define NEXP   256
#define TOPKG  4
#define TOPK   8
#define NSPLIT 4
#define KCHUNK (DIM / NSPLIT)   // 1024
#define BM     256              // tokens per block
#define BK     32
#define ALD    34               // A row stride in shorts (17 dwords, coprime 32 banks)

typedef float v4f    __attribute__((ext_vector_type(4)));
typedef short short8 __attribute__((ext_vector_type(8)));

__device__ inline unsigned short f2bf(float x) {           // round-to-nearest-even
    unsigned u = __float_as_uint(x);
    return (unsigned short)((u + 0x7fffu + ((u >> 16) & 1u)) >> 16);
}
__device__ inline float bf2f(unsigned short h) {
    return __uint_as_float(((unsigned)h) << 16);
}

// ---- W fp32 -> bf16 (hi, lo) row-major [256][4096], once per call ----
__global__ __launch_bounds__(256) void wprep(const float* __restrict__ W,
                                             unsigned short* __restrict__ Wh,
                                             unsigned short* __restrict__ Wl) {
    int i = (blockIdx.x * 256 + threadIdx.x) * 4;
    float4 v = *(const float4*)(W + i);
    ushort4 h, l;
    h.x = f2bf(v.x); l.x = f2bf(v.x - bf2f(h.x));
    h.y = f2bf(v.y); l.y = f2bf(v.y - bf2f(h.y));
    h.z = f2bf(v.z); l.z = f2bf(v.z - bf2f(h.z));
    h.w = f2bf(v.w); l.w = f2bf(v.w - bf2f(h.w));
    *(ushort4*)(Wh + i) = h;
    *(ushort4*)(Wl + i) = l;
}

// ---- GEMM: P[z][t][e], bf16x2 3-pass MFMA. Tile 256x256, 4 waves of 128x128.
// Same K-chain order as round 4 -> P bitwise identical (no top-k re-roll).
__global__ __launch_bounds__(256, 1) void gate_gemm(const float* __restrict__ X,
                                                    const unsigned short* __restrict__ Wh,
                                                    const unsigned short* __restrict__ Wl,
                                                    float* __restrict__ P) {
    __shared__ __align__(16) unsigned short Ah[BM * ALD];   // 17 KB, padded stride
    __shared__ __align__(16) unsigned short Al[BM * ALD];
    __shared__ __align__(16) unsigned short Bh[NEXP * BK];  // 16 KB, DMA-contiguous
    __shared__ __align__(16) unsigned short Bl[NEXP * BK];

    const int t  = threadIdx.x;
    const int bm = blockIdx.x * BM;
    const int z  = blockIdx.y;
    const int k0 = z * KCHUNK;

    const int l  = t & 63;
    const int w  = t >> 6;
    const int wr = w >> 1;     // wave row (0..1): token rows wr*128..+127
    const int wc = w & 1;      // wave col (0..1): experts wc*128..+127
    const int lm = l & 15;
    const int lq = l >> 4;

    // A staging: thread t owns token row t (32 k fp32 per round)
    const float* xrow = X + (size_t)(bm + t) * DIM + k0;

    float4 xv[8];
#pragma unroll
    for (int i = 0; i < 8; ++i) xv[i] = *(const float4*)(xrow + i * 4);

    v4f acc[8][8] = {};

    for (int kr = 0; kr < KCHUNK; kr += BK) {
        __syncthreads();   // prior round's frag reads done; A-prefetch drained (long past)

        // B: bf16 h/l direct global->LDS (W chunk L2-resident after first sweep)
#pragma unroll
        for (int i = 0; i < 4; ++i) {
            int flat = i * 256 + t;            // e*4+q, e=expert, q=k-octet
            const unsigned short* gh = Wh + (size_t)(flat >> 2) * DIM + k0 + kr + (flat & 3) * 8;
            const unsigned short* gl = Wl + (size_t)(flat >> 2) * DIM + k0 + kr + (flat & 3) * 8;
            __builtin_amdgcn_global_load_lds(
                (const __attribute__((address_space(1))) unsigned int*)gh,
                (__attribute__((address_space(3))) unsigned int*)&Bh[flat * 8], 16, 0, 0);
            __builtin_amdgcn_global_load_lds(
                (const __attribute__((address_space(1))) unsigned int*)gl,
                (__attribute__((address_space(3))) unsigned int*)&Bl[flat * 8], 16, 0, 0);
        }

        // A: split-convert this round's prefetched regs, stage to padded LDS
#pragma unroll
        for (int i = 0; i < 8; ++i) {
            ushort4 h, lo;
            h.x = f2bf(xv[i].x); lo.x = f2bf(xv[i].x - bf2f(h.x));
            h.y = f2bf(xv[i].y); lo.y = f2bf(xv[i].y - bf2f(h.y));
            h.z = f2bf(xv[i].z); lo.z = f2bf(xv[i].z - bf2f(h.z));
            h.w = f2bf(xv[i].w); lo.w = f2bf(xv[i].w - bf2f(h.w));
            *(ushort4*)&Ah[t * ALD + i * 4] = h;
            *(ushort4*)&Al[t * ALD + i * 4] = lo;
        }

        __syncthreads();   // B DMA + A stores visible

        // prefetch next round's A AFTER the barrier: latency hides under 192 MFMAs
        if (kr + BK < KCHUNK) {
#pragma unroll
            for (int i = 0; i < 8; ++i) xv[i] = *(const float4*)(xrow + kr + BK + i * 4);
        }

        short8 bh[8], bl[8];
#pragma unroll
        for (int c = 0; c < 8; ++c) {
            int e = wc * 128 + c * 16 + lm;
            bh[c] = *(const short8*)&Bh[e * BK + lq * 8];
            bl[c] = *(const short8*)&Bl[e * BK + lq * 8];
        }
#pragma unroll
        for (int r = 0; r < 8; ++r) {
            int m = wr * 128 + r * 16 + lm;
            short8 ah = *(const short8*)&Ah[m * ALD + lq * 8];
            short8 al = *(const short8*)&Al[m * ALD + lq * 8];
#pragma unroll
            for (int c = 0; c < 8; ++c) {
                acc[r][c] = __builtin_amdgcn_mfma_f32_16x16x32_bf16(ah, bh[c], acc[r][c], 0, 0, 0);
                acc[r][c] = __builtin_amdgcn_mfma_f32_16x16x32_bf16(ah, bl[c], acc[r][c], 0, 0, 0);
                acc[r][c] = __builtin_amdgcn_mfma_f32_16x16x32_bf16(al, bh[c], acc[r][c], 0, 0, 0);
            }
        }
    }

    // epilogue: C/D layout col=lane&15, row=lq*4+reg (verified m89/m91)
    float* Pb = P + ((size_t)z * NTOK + bm) * NEXP;
#pragma unroll
    for (int r = 0; r < 8; ++r)
#pragma unroll
        for (int c = 0; c < 8; ++c)
#pragma unroll
            for (int g = 0; g < 4; ++g)
                Pb[(size_t)(wr * 128 + r * 16 + lq * 4 + g) * NEXP + wc * 128 + c * 16 + lm]
                    = acc[r][c][g];
}

// ---- fused reduce (4 partials, fixed order) + routing: one wave per token ----
__global__ __launch_bounds__(256) void gate_route(const float* __restrict__ P,
                                                  float* __restrict__ outw,
                                                  float* __restrict__ outi) {
    const int lane = threadIdx.x & 63;
    const int tok  = (blockIdx.x * blockDim.x + threadIdx.x) >> 6;
    if (tok >= NTOK) return;

    float l[4] = {0.f, 0.f, 0.f, 0.f};
#pragma unroll
    for (int z = 0; z < NSPLIT; ++z) {   // fixed order: deterministic
        float4 v = *(const float4*)(P + ((size_t)z * NTOK + tok) * NEXP + lane * 4);
        l[0] += v.x; l[1] += v.y; l[2] += v.z; l[3] += v.w;
    }

    float lmax = fmaxf(fmaxf(l[0], l[1]), fmaxf(l[2], l[3]));
    float m = lmax;
#pragma unroll
    for (int o = 32; o; o >>= 1) m = fmaxf(m, __shfl_xor(m, o));

    float s = __expf(l[0] - m) + __expf(l[1] - m) + __expf(l[2] - m) + __expf(l[3] - m);
#pragma unroll
    for (int o = 32; o; o >>= 1) s += __shfl_xor(s, o);

    float gm = lmax;
#pragma unroll
    for (int o = 4; o; o >>= 1) gm = fmaxf(gm, __shfl_xor(gm, o));

    const int g = lane >> 3;
    int rank = 0;
#pragma unroll
    for (int gg = 0; gg < 8; ++gg) {
        float vg = __shfl(gm, gg * 8);
        rank += (vg > gm) || (vg == gm && gg < g);
    }
    const bool allowed = rank < TOPKG;

    float mv[4];
#pragma unroll
    for (int j = 0; j < 4; ++j) mv[j] = allowed ? l[j] : -INFINITY;

    float wsel = 0.0f;
    int   isel = 0;

    for (int k = 0; k < TOPK; ++k) {
        float bv = mv[0];
        int   bi = lane * 4;
        if (mv[1] > bv) { bv = mv[1]; bi = lane * 4 + 1; }
        if (mv[2] > bv) { bv = mv[2]; bi = lane * 4 + 2; }
        if (mv[3] > bv) { bv = mv[3]; bi = lane * 4 + 3; }
#pragma unroll
        for (int o = 32; o; o >>= 1) {
            float ov = __shfl_xor(bv, o);
            int   oi = __shfl_xor(bi, o);
            if (ov > bv || (ov == bv && oi < bi)) { bv = ov; bi = oi; }
        }
        if (lane == k) { wsel = __expf(bv - m) / s; isel = bi; }
        if ((bi >> 2) == lane) mv[bi & 3] = -INFINITY;
    }

    if (lane < TOPK) {
        outw[(size_t)tok * TOPK + lane] = wsel;
        outi[(size_t)tok * TOPK + lane] = (float)isel;
    }
}

extern "C" void kernel_launch(void* const* d_in, const int* in_sizes, int n_in,
                              void* d_out, int out_size, void* d_ws, size_t ws_size,
                              hipStream_t stream) {
    const float* x  = (const float*)d_in[0];   // [16384, 4096]
    const float* wt = (const float*)d_in[1];   // [256, 4096]

    // ws: partials [4][16384][256] f32 (64 MB) | Wh (2 MB) | Wl (2 MB)
    float* P = (float*)d_ws;
    unsigned short* Wh = (unsigned short*)((char*)d_ws + (size_t)NSPLIT * NTOK * NEXP * 4);
    unsigned short* Wl = Wh + (size_t)NEXP * DIM;

    float* outw = (float*)d_out;
    float* outi = (float*)d_out + (size_t)NTOK * TOPK;

    wprep<<<(NEXP * DIM) / (256 * 4), 256, 0, stream>>>(wt, Wh, Wl);

    dim3 ggrid(NTOK / BM, NSPLIT);   // (64, 4) = 256 blocks, 1/CU
    gate_gemm<<<ggrid, 256, 0, stream>>>(x, Wh, Wl, P);

    gate_route<<<(NTOK * 64) / 256, 256, 0, stream>>>(P, outw, outi);
}